// Round 3
// baseline (45.116 us; speedup 1.0000x reference)
//
#include <hip/hip_runtime.h>

// YIN pitch, B=8, n=80000, fp32.
// SR=8000 HOP=80 TAU_MIN=20 TAU_MAX=133 W=133 FRAME_LEN=266 THRESH=0.2
// n_frames=997, output keeps 996 per batch.
//
// v3: single shared stream g[i]=f[lane+1+i] feeds BOTH tau=lane+1 (i<=132)
// and tau=lane+65 (i>=64) -> 197 LDS dwords/lane instead of 266.
// Broadcast operand f[j] read from GLOBAL via uniform pointer
// (readfirstlane(waveid)) -> s_load on the SMEM pipe, off the LDS pipe.

#define SR_F      8000.0f
#define HOP       80
#define TAU_MIN   20
#define FRAME_LEN 266
#define NF_OUT    996
#define NSAMP     80000
#define THRESH    0.2f
#define FPB       4
#define CHUNK     (FRAME_LEN + (FPB - 1) * HOP)   // 506 floats
#define BPB       (NF_OUT / FPB)                  // 249 blocks per batch

__global__ __launch_bounds__(256) void yin_kernel(const float* __restrict__ x,
                                                  float* __restrict__ out) {
    const int bx = blockIdx.x;
    const int b  = bx / BPB;
    const int fb = bx - b * BPB;
    const int frame0 = fb * FPB;
    const float* __restrict__ xrow = x + (size_t)b * NSAMP + (size_t)frame0 * HOP;

    __shared__ float sch[CHUNK];
    const int t = threadIdx.x;
    for (int i = t; i < CHUNK; i += 256) sch[i] = xrow[i];
    __syncthreads();

    const int lane = t & 63;
    // wave id, made provably uniform so fr[] loads scalarize (s_load)
    const int wu = __builtin_amdgcn_readfirstlane(t >> 6);
    const float* __restrict__ fr = xrow + wu * HOP;        // uniform (SMEM pipe)
    const float* __restrict__ f  = sch  + wu * HOP;        // LDS, per-lane use
    const float* __restrict__ g  = f + lane + 1;           // per-lane stream

    // ---- difference fn: tau_a = lane+1 (A), tau_b = lane+65 (B) ----
    float A0 = 0.f, A1 = 0.f, B0 = 0.f, B1 = 0.f;
    #pragma unroll
    for (int i = 0; i < 64; i += 2) {           // A only
        float d0 = fr[i]     - g[i];     A0 = fmaf(d0, d0, A0);
        float d1 = fr[i + 1] - g[i + 1]; A1 = fmaf(d1, d1, A1);
    }
    #pragma unroll
    for (int i = 64; i < 132; i += 2) {         // A and B share the stream
        float ga = g[i], gb = g[i + 1];
        float d0 = fr[i]      - ga; A0 = fmaf(d0, d0, A0);
        float d1 = fr[i + 1]  - gb; A1 = fmaf(d1, d1, A1);
        float e0 = fr[i - 64] - ga; B0 = fmaf(e0, e0, B0);
        float e1 = fr[i - 63] - gb; B1 = fmaf(e1, e1, B1);
    }
    {   // i = 132
        float ga = g[132];
        float d0 = fr[132] - ga; A0 = fmaf(d0, d0, A0);
        float e0 = fr[68]  - ga; B0 = fmaf(e0, e0, B0);
    }
    #pragma unroll
    for (int i = 133; i < 197; i += 2) {        // B only
        float ga = g[i], gb = g[i + 1];
        float e0 = fr[i - 64] - ga; B0 = fmaf(e0, e0, B0);
        float e1 = fr[i - 63] - gb; B1 = fmaf(e1, e1, B1);
    }
    float dA = A0 + A1;   // d[lane+1]
    float dB = B0 + B1;   // d[lane+65]

    // ---- taus 129..133: j split across lanes (j = lane, lane+64, lane+128) ----
    float p[5] = {0.f, 0.f, 0.f, 0.f, 0.f};
    {
        float base0 = f[lane];
        float base1 = f[lane + 64];
        const float* g0 = f + 129 + lane;
        const float* g1 = f + 129 + lane + 64;
        #pragma unroll
        for (int k = 0; k < 5; ++k) {
            float d0 = base0 - g0[k]; p[k] = fmaf(d0, d0, p[k]);
            float d1 = base1 - g1[k]; p[k] = fmaf(d1, d1, p[k]);
        }
        if (lane < 5) {
            float base2 = f[lane + 128];
            const float* g2 = f + 129 + lane + 128;
            #pragma unroll
            for (int k = 0; k < 5; ++k) {
                float d2 = base2 - g2[k]; p[k] = fmaf(d2, d2, p[k]);
            }
        }
    }
    #pragma unroll
    for (int k = 0; k < 5; ++k) {
        #pragma unroll
        for (int off = 32; off; off >>= 1) p[k] += __shfl_xor(p[k], off);
    }   // p[k] = d[129+k], uniform across wave

    // ---- CMNDF: inclusive prefix scan of d over lanes (registers only) ----
    float sA = dA, sB = dB;
    #pragma unroll
    for (int off = 1; off < 64; off <<= 1) {
        float uA = __shfl_up(sA, off);
        float uB = __shfl_up(sB, off);
        if (lane >= off) { sA += uA; sB += uB; }
    }
    float total0 = __shfl(sA, 63);          // cum[64]
    float cumA = sA;                        // cum[lane+1]
    float cumB = total0 + sB;               // cum[lane+65]
    float total1 = __shfl(cumB, 63);        // cum[128]

    float cmA = dA * (float)(lane + 1)  / fmaxf(cumA, 1e-8f);
    float cmB = dB * (float)(lane + 65) / fmaxf(cumB, 1e-8f);
    bool candA = (lane >= (TAU_MIN - 1)) && (cmA < THRESH);  // tau_a >= 20
    bool candB = (cmB < THRESH);                             // tau_b >= 65 always
    unsigned long long mA = __ballot(candA);
    unsigned long long mB = __ballot(candB);

    int tau = 0;
    if (mA) {
        tau = __ffsll((unsigned long long)mA);        // lane+1
    } else if (mB) {
        tau = __ffsll((unsigned long long)mB) + 64;   // lane+65
    } else {
        float c = total1;
        #pragma unroll
        for (int k = 0; k < 5; ++k) {
            c += p[k];
            float cm = p[k] * (float)(129 + k) / fmaxf(c, 1e-8f);
            if (tau == 0 && cm < THRESH) tau = 129 + k;
        }
    }

    if (lane == 0) {
        float f0v = (tau > 0) ? (SR_F / (float)tau) : 0.0f;
        out[(size_t)b * NF_OUT + frame0 + wu] = f0v;
    }
}

extern "C" void kernel_launch(void* const* d_in, const int* in_sizes, int n_in,
                              void* d_out, int out_size, void* d_ws, size_t ws_size,
                              hipStream_t stream) {
    (void)in_sizes; (void)n_in; (void)d_ws; (void)ws_size; (void)out_size;
    const float* x = (const float*)d_in[0];
    float* out = (float*)d_out;
    yin_kernel<<<dim3(8 * BPB), dim3(256), 0, stream>>>(x, out);
}

// Round 4
// 15.650 us; speedup vs baseline: 2.8828x; 2.8828x over previous
//
#include <hip/hip_runtime.h>

// YIN pitch, B=8, n=80000, fp32. SR=8000 HOP=80 TAU_MIN=20 TAU_MAX=133 W=133
// FRAME_LEN=266 THRESH=0.2 ; n_frames=997, output 996/batch.
//
// v4: 192 thr = 3 waves = 6 frames/block (one frame per 32-lane half-wave).
// Lane (l2=lane&31) owns tau = 4*l2+1..4*l2+4  (covers 1..128; tail 129..133
// via j-split + DPP reduce). Stream reads are ds_read_b128 (16B aligned),
// broadcast reads are ds_read_b128 uniform-per-half. ALL cross-lane ops
// (cum prefix scan, tail reduce, argmin pick) use DPP on the VALU pipe —
// zero DS-pipe shuffles. No divides: d*tau < 0.2*max(cum,eps).

#define NF_OUT 996
#define NSAMP  80000
#define FPB    6
#define BPB    (NF_OUT / FPB)   // 166
#define CHUNKD 672              // 266 + 5*80 = 666, padded to 16B multiple
#define TH     0.2f
#define EPS    1e-8f

template<int CTRL>
__device__ __forceinline__ float dpp_add_f(float x) {
    int t = __builtin_amdgcn_update_dpp(0, __builtin_bit_cast(int, x), CTRL, 0xF, 0xF, false);
    return x + __builtin_bit_cast(float, t);
}
__device__ __forceinline__ float dpp_b15_add_f(float x) {   // rows 1,3 += lane15/47
    int t = __builtin_amdgcn_update_dpp(0, __builtin_bit_cast(int, x), 0x142, 0xA, 0xF, false);
    return x + __builtin_bit_cast(float, t);
}
template<int CTRL>
__device__ __forceinline__ int dpp_min_i(int x) {
    int t = __builtin_amdgcn_update_dpp(0x7FFFFFFF, x, CTRL, 0xF, 0xF, false);
    return (t < x) ? t : x;
}
__device__ __forceinline__ int dpp_b15_min_i(int x) {
    int t = __builtin_amdgcn_update_dpp(0x7FFFFFFF, x, 0x142, 0xA, 0xF, false);
    return (t < x) ? t : x;
}
// inclusive 32-lane scan (per half-wave); lane31/63 end with the half's total
__device__ __forceinline__ float scan32_add(float v) {
    v = dpp_add_f<0x111>(v);   // row_shr:1
    v = dpp_add_f<0x112>(v);   // row_shr:2
    v = dpp_add_f<0x114>(v);   // row_shr:4
    v = dpp_add_f<0x118>(v);   // row_shr:8
    v = dpp_b15_add_f(v);
    return v;
}
__device__ __forceinline__ int red32_min(int v) {
    v = dpp_min_i<0x111>(v);
    v = dpp_min_i<0x112>(v);
    v = dpp_min_i<0x114>(v);
    v = dpp_min_i<0x118>(v);
    v = dpp_b15_min_i(v);
    return v;
}

#define MAC4(CURV, NXTV, FRV) do {                                             \
    float w0=CURV.y,w1=CURV.z,w2=CURV.w,w3=NXTV.x,w4=NXTV.y,w5=NXTV.z,w6=NXTV.w; \
    float d_;                                                                  \
    d_=FRV.x-w0; a0=fmaf(d_,d_,a0); d_=FRV.y-w1; a0=fmaf(d_,d_,a0);            \
    d_=FRV.z-w2; a0=fmaf(d_,d_,a0); d_=FRV.w-w3; a0=fmaf(d_,d_,a0);            \
    d_=FRV.x-w1; a1=fmaf(d_,d_,a1); d_=FRV.y-w2; a1=fmaf(d_,d_,a1);            \
    d_=FRV.z-w3; a1=fmaf(d_,d_,a1); d_=FRV.w-w4; a1=fmaf(d_,d_,a1);            \
    d_=FRV.x-w2; a2=fmaf(d_,d_,a2); d_=FRV.y-w3; a2=fmaf(d_,d_,a2);            \
    d_=FRV.z-w4; a2=fmaf(d_,d_,a2); d_=FRV.w-w5; a2=fmaf(d_,d_,a2);            \
    d_=FRV.x-w3; a3=fmaf(d_,d_,a3); d_=FRV.y-w4; a3=fmaf(d_,d_,a3);            \
    d_=FRV.z-w5; a3=fmaf(d_,d_,a3); d_=FRV.w-w6; a3=fmaf(d_,d_,a3);            \
} while (0)

__global__ __launch_bounds__(192) void yin_kernel(const float* __restrict__ x,
                                                  float* __restrict__ out) {
    const int bx = blockIdx.x;
    const int b  = bx / BPB;
    const int fb = bx - b * BPB;
    const float* __restrict__ xrow = x + (size_t)b * NSAMP + (size_t)fb * (FPB * 80);

    __shared__ __align__(16) float sch[CHUNKD];
    const int t = threadIdx.x;
    {
        int t4 = t * 4;
        if (t4 < CHUNKD)
            *(float4*)(sch + t4) = *(const float4*)(xrow + t4);
    }
    __syncthreads();

    const int lane = t & 63;
    const int w    = t >> 6;        // wave id 0..2
    const int h    = lane >> 5;     // half: frame select
    const int l2   = lane & 31;
    const float* f  = sch + (2 * w + h) * 80;   // this half's frame
    const float* gp = f + 4 * l2;               // stream base (16B aligned)

    // ---- difference fn: tau = 4*l2+1 .. 4*l2+4 ----
    float4 cur = *(const float4*)(gp);          // stream chunk 0 (m=0..3)
    const float4 S0 = cur;                      // f[4*l2 + 0..3]  (tail j's)
    float4 nxt;
    float a0 = 0.f, a1 = 0.f, a2 = 0.f, a3 = 0.f;

    #pragma unroll 4
    for (int c = 0; c < 32; ++c) {              // j = 4c+q, q=0..3 (j<=127+4)
        nxt = *(const float4*)(gp + 4 * (c + 1));
        float4 fr = *(const float4*)(f + 4 * c);
        MAC4(cur, nxt, fr);
        cur = nxt;
    }
    const float4 C32 = cur;                     // stream m = 128..131
    {   // c = 32 (j = 128..131)
        nxt = *(const float4*)(gp + 4 * 33);
        float4 fr = *(const float4*)(f + 128);
        MAC4(cur, nxt, fr);
        cur = nxt;
    }
    const float4 C33 = cur;                     // m = 132..135
    const float4 C34 = *(const float4*)(gp + 4 * 34);   // m = 136..139
    {   // c = 33, q = 0 only (j = 132): m = 133+t
        float frx = f[132];
        float d_;
        d_ = frx - C33.y; a0 = fmaf(d_, d_, a0);
        d_ = frx - C33.z; a1 = fmaf(d_, d_, a1);
        d_ = frx - C33.w; a2 = fmaf(d_, d_, a2);
        d_ = frx - C34.x; a3 = fmaf(d_, d_, a3);
    }

    // ---- tail taus 129..133: d[129+k] = sum_j (f[j]-f[129+k+j])^2 ----
    // per-lane j = 4*l2+q (j=0..127); m = 129+k+q in [129,136]
    float sm[8] = {C32.y, C32.z, C32.w, C33.x, C33.y, C33.z, C33.w, C34.x};
    float s0a[4] = {S0.x, S0.y, S0.z, S0.w};
    float p[5] = {0.f, 0.f, 0.f, 0.f, 0.f};
    #pragma unroll
    for (int k = 0; k < 5; ++k) {
        #pragma unroll
        for (int q = 0; q < 4; ++q) {
            float d_ = s0a[q] - sm[k + q];
            p[k] = fmaf(d_, d_, p[k]);
        }
    }
    if (l2 < 5) {   // leftover j = 128..132, one per lane
        float av = f[128 + l2];
        #pragma unroll
        for (int k = 0; k < 5; ++k) {
            float d_ = av - f[257 + l2 + k];
            p[k] = fmaf(d_, d_, p[k]);
        }
    }
    #pragma unroll
    for (int k = 0; k < 5; ++k) p[k] = scan32_add(p[k]);   // total at lane31/63

    // ---- CMNDF cum prefix (registers + DPP) ----
    float L = a0 + a1 + a2 + a3;
    float inc = scan32_add(L);
    float excl = inc - L;
    float c0 = excl + a0;
    float c1 = c0 + a1;
    float c2 = c1 + a2;
    float c3 = c2 + a3;

    // ---- candidate pick: cmndf<0.2 & tau>=20 ;  d*tau < TH*max(cum,eps) ----
    int best = 0x7FFFFFFF;
    const int tau0 = 4 * l2 + 1;
    if (tau0     >= 20 && a0 * (float)(tau0)     < TH * fmaxf(c0, EPS)) best = tau0;
    if (best == 0x7FFFFFFF && tau0 + 1 >= 20 && a1 * (float)(tau0 + 1) < TH * fmaxf(c1, EPS)) best = tau0 + 1;
    if (best == 0x7FFFFFFF && tau0 + 2 >= 20 && a2 * (float)(tau0 + 2) < TH * fmaxf(c2, EPS)) best = tau0 + 2;
    if (best == 0x7FFFFFFF && tau0 + 3 >= 20 && a3 * (float)(tau0 + 3) < TH * fmaxf(c3, EPS)) best = tau0 + 3;

    if (l2 == 31) {     // this lane holds cum[128] and the reduced p[k]
        float cum = c3;
        #pragma unroll
        for (int k = 0; k < 5; ++k) {
            cum += p[k];
            if (p[k] * (float)(129 + k) < TH * fmaxf(cum, EPS))
                best = (best < 129 + k) ? best : (129 + k);
        }
    }
    best = red32_min(best);     // half-wave min -> lane31/63

    if (l2 == 31) {
        int fr_idx = fb * FPB + 2 * w + h;
        out[(size_t)b * NF_OUT + fr_idx] =
            (best == 0x7FFFFFFF) ? 0.0f : 8000.0f / (float)best;
    }
}

extern "C" void kernel_launch(void* const* d_in, const int* in_sizes, int n_in,
                              void* d_out, int out_size, void* d_ws, size_t ws_size,
                              hipStream_t stream) {
    (void)in_sizes; (void)n_in; (void)d_ws; (void)ws_size; (void)out_size;
    const float* x = (const float*)d_in[0];
    float* out = (float*)d_out;
    yin_kernel<<<dim3(8 * BPB), dim3(192), 0, stream>>>(x, out);
}

// Round 5
// 15.197 us; speedup vs baseline: 2.9686x; 1.0298x over previous
//
#include <hip/hip_runtime.h>

// YIN pitch, B=8, n=80000, fp32. SR=8000 HOP=80 TAU_MIN=20 TAU_MAX=133 W=133
// FRAME_LEN=266 THRESH=0.2 ; n_frames=997, output 996/batch.
//
// v5: correlation form. d(tau) = EA + EB(tau) - 2*r(tau), with
//   r(tau)  = sum_j f[j]*f[j+tau]          (16 fma / 4-j chunk, no subs)
//   EB(tau) = running sum Q of stream squares (4 fma/chunk) + edge terms
//   EA      = sum_{j<133} f[j]^2 (per-lane square + DPP scan + 1 shfl bcast)
// Structure otherwise = v4: 192 thr = 3 waves = 6 frames/block, half-wave per
// frame, lane owns tau = 4*l2+1..4*l2+4; tail taus 129..133 j-split; all
// cross-lane via DPP; no divides. __launch_bounds__(192,4) caps VGPR at 128.

#define NF_OUT 996
#define NSAMP  80000
#define FPB    6
#define BPB    (NF_OUT / FPB)   // 166
#define CHUNKD 672              // staged samples per block (16B padded)
#define TH     0.2f
#define EPS    1e-8f

template<int CTRL>
__device__ __forceinline__ float dpp_add_f(float x) {
    int t = __builtin_amdgcn_update_dpp(0, __builtin_bit_cast(int, x), CTRL, 0xF, 0xF, false);
    return x + __builtin_bit_cast(float, t);
}
__device__ __forceinline__ float dpp_b15_add_f(float x) {   // rows 1,3 += lane15/47
    int t = __builtin_amdgcn_update_dpp(0, __builtin_bit_cast(int, x), 0x142, 0xA, 0xF, false);
    return x + __builtin_bit_cast(float, t);
}
template<int CTRL>
__device__ __forceinline__ int dpp_min_i(int x) {
    int t = __builtin_amdgcn_update_dpp(0x7FFFFFFF, x, CTRL, 0xF, 0xF, false);
    return (t < x) ? t : x;
}
__device__ __forceinline__ int dpp_b15_min_i(int x) {
    int t = __builtin_amdgcn_update_dpp(0x7FFFFFFF, x, 0x142, 0xA, 0xF, false);
    return (t < x) ? t : x;
}
// inclusive 32-lane scan (per half-wave); lane31/63 end with the half's total
__device__ __forceinline__ float scan32_add(float v) {
    v = dpp_add_f<0x111>(v);
    v = dpp_add_f<0x112>(v);
    v = dpp_add_f<0x114>(v);
    v = dpp_add_f<0x118>(v);
    v = dpp_b15_add_f(v);
    return v;
}
__device__ __forceinline__ int red32_min(int v) {
    v = dpp_min_i<0x111>(v);
    v = dpp_min_i<0x112>(v);
    v = dpp_min_i<0x114>(v);
    v = dpp_min_i<0x118>(v);
    v = dpp_b15_min_i(v);
    return v;
}

// correlation MAC: r_q += fr[jj] * w_{jj+q}; Q += nxt^2 terms. 20 fma total.
#define MACR(CURV, NXTV, FRV) do {                                             \
    float w0=CURV.y,w1=CURV.z,w2=CURV.w,w3=NXTV.x,w4=NXTV.y,w5=NXTV.z,w6=NXTV.w; \
    r0 = fmaf(FRV.x,w0,r0); r1 = fmaf(FRV.x,w1,r1);                            \
    r2 = fmaf(FRV.x,w2,r2); r3 = fmaf(FRV.x,w3,r3);                            \
    r0 = fmaf(FRV.y,w1,r0); r1 = fmaf(FRV.y,w2,r1);                            \
    r2 = fmaf(FRV.y,w3,r2); r3 = fmaf(FRV.y,w4,r3);                            \
    r0 = fmaf(FRV.z,w2,r0); r1 = fmaf(FRV.z,w3,r1);                            \
    r2 = fmaf(FRV.z,w4,r2); r3 = fmaf(FRV.z,w5,r3);                            \
    r0 = fmaf(FRV.w,w3,r0); r1 = fmaf(FRV.w,w4,r1);                            \
    r2 = fmaf(FRV.w,w5,r2); r3 = fmaf(FRV.w,w6,r3);                            \
    Q  = fmaf(NXTV.x,NXTV.x,Q); Q = fmaf(NXTV.y,NXTV.y,Q);                     \
    Q  = fmaf(NXTV.z,NXTV.z,Q); Q = fmaf(NXTV.w,NXTV.w,Q);                     \
} while (0)

__global__ __launch_bounds__(192, 4) void yin_kernel(const float* __restrict__ x,
                                                     float* __restrict__ out) {
    const int bx = blockIdx.x;
    const int b  = bx / BPB;
    const int fb = bx - b * BPB;
    const float* __restrict__ xrow = x + (size_t)b * NSAMP + (size_t)fb * (FPB * 80);

    __shared__ __align__(16) float sch[CHUNKD];
    const int t = threadIdx.x;
    {
        int t4 = t * 4;
        if (t4 < CHUNKD)
            *(float4*)(sch + t4) = *(const float4*)(xrow + t4);
    }
    __syncthreads();

    const int lane = t & 63;
    const int w    = t >> 6;        // wave id 0..2
    const int h    = lane >> 5;     // half: frame select
    const int l2   = lane & 31;
    const float* f  = sch + (2 * w + h) * 80;   // this half's frame
    const float* gp = f + 4 * l2;               // stream base (16B aligned)

    // ---- r(tau) + Q, tau = 4*l2+1 .. 4*l2+4 ----
    float4 cur = *(const float4*)(gp);          // chunk 0 (m=0..3)
    const float4 S0 = cur;
    float4 nxt;
    float r0 = 0.f, r1 = 0.f, r2 = 0.f, r3 = 0.f, Q = 0.f;

    #pragma unroll 4
    for (int c = 0; c < 32; ++c) {              // j = 4c..4c+3 (j<=127)
        nxt = *(const float4*)(gp + 4 * (c + 1));
        float4 fr = *(const float4*)(f + 4 * c);
        MACR(cur, nxt, fr);
        cur = nxt;
    }
    const float4 C32 = cur;                     // stream m = 128..131
    float4 FR32;
    {   // c = 32 (j = 128..131)
        nxt = *(const float4*)(gp + 4 * 33);
        FR32 = *(const float4*)(f + 128);
        MACR(cur, nxt, FR32);
        cur = nxt;
    }
    const float4 C33 = cur;                     // m = 132..135
    const float4 C34 = *(const float4*)(gp + 4 * 34);   // m = 136..139
    const float frx = f[132];
    {   // j = 132
        r0 = fmaf(frx, C33.y, r0);
        r1 = fmaf(frx, C33.z, r1);
        r2 = fmaf(frx, C33.w, r2);
        r3 = fmaf(frx, C34.x, r3);
    }

    // ---- EB(tau): Q covers stream m'=4..135; adjust edges ----
    const float sy = S0.y * S0.y, sz = S0.z * S0.z, sw = S0.w * S0.w;
    const float zC = C33.z * C33.z, wC = C33.w * C33.w, x34 = C34.x * C34.x;
    const float EB0 = Q + sy + sz + sw - zC - wC;   // m' 1..133
    const float EB1 = Q + sz + sw - wC;             // m' 2..134
    const float EB2 = Q + sw;                       // m' 3..135
    const float EB3 = Q + x34;                      // m' 4..136

    // ---- EA = sum_{j<133} f[j]^2 (per half uniform) ----
    float sq4 = fmaf(S0.x, S0.x, fmaf(S0.y, S0.y, fmaf(S0.z, S0.z, S0.w * S0.w)));
    float tot128 = __shfl(scan32_add(sq4), 31, 32);   // sum_{j<128}, all lanes
    float EA = tot128 + FR32.x * FR32.x + FR32.y * FR32.y
             + FR32.z * FR32.z + FR32.w * FR32.w + frx * frx;

    // ---- d(tau) ----
    const float a0 = fmaf(-2.f, r0, EA + EB0);
    const float a1 = fmaf(-2.f, r1, EA + EB1);
    const float a2 = fmaf(-2.f, r2, EA + EB2);
    const float a3 = fmaf(-2.f, r3, EA + EB3);

    // ---- tail taus 129..133 (direct form, j-split) ----
    float sm[8] = {C32.y, C32.z, C32.w, C33.x, C33.y, C33.z, C33.w, C34.x};
    float s0a[4] = {S0.x, S0.y, S0.z, S0.w};
    float p[5] = {0.f, 0.f, 0.f, 0.f, 0.f};
    #pragma unroll
    for (int k = 0; k < 5; ++k) {
        #pragma unroll
        for (int q = 0; q < 4; ++q) {
            float d_ = s0a[q] - sm[k + q];
            p[k] = fmaf(d_, d_, p[k]);
        }
    }
    if (l2 < 5) {   // leftover j = 128..132, one per lane
        float av = f[128 + l2];
        #pragma unroll
        for (int k = 0; k < 5; ++k) {
            float d_ = av - f[257 + l2 + k];
            p[k] = fmaf(d_, d_, p[k]);
        }
    }
    #pragma unroll
    for (int k = 0; k < 5; ++k) p[k] = scan32_add(p[k]);   // total at lane31/63

    // ---- CMNDF cum prefix (registers + DPP) ----
    float L = a0 + a1 + a2 + a3;
    float inc = scan32_add(L);
    float excl = inc - L;
    float c0 = excl + a0;
    float c1 = c0 + a1;
    float c2 = c1 + a2;
    float c3 = c2 + a3;

    // ---- candidate pick: d*tau < TH*max(cum,eps), tau >= 20 ----
    int best = 0x7FFFFFFF;
    const int tau0 = 4 * l2 + 1;
    if (tau0     >= 20 && a0 * (float)(tau0)     < TH * fmaxf(c0, EPS)) best = tau0;
    if (best == 0x7FFFFFFF && tau0 + 1 >= 20 && a1 * (float)(tau0 + 1) < TH * fmaxf(c1, EPS)) best = tau0 + 1;
    if (best == 0x7FFFFFFF && tau0 + 2 >= 20 && a2 * (float)(tau0 + 2) < TH * fmaxf(c2, EPS)) best = tau0 + 2;
    if (best == 0x7FFFFFFF && tau0 + 3 >= 20 && a3 * (float)(tau0 + 3) < TH * fmaxf(c3, EPS)) best = tau0 + 3;

    if (l2 == 31) {     // this lane holds cum[128] and the reduced p[k]
        float cum = c3;
        #pragma unroll
        for (int k = 0; k < 5; ++k) {
            cum += p[k];
            if (p[k] * (float)(129 + k) < TH * fmaxf(cum, EPS))
                best = (best < 129 + k) ? best : (129 + k);
        }
    }
    best = red32_min(best);     // half-wave min -> lane31/63

    if (l2 == 31) {
        int fr_idx = fb * FPB + 2 * w + h;
        out[(size_t)b * NF_OUT + fr_idx] =
            (best == 0x7FFFFFFF) ? 0.0f : 8000.0f / (float)best;
    }
}

extern "C" void kernel_launch(void* const* d_in, const int* in_sizes, int n_in,
                              void* d_out, int out_size, void* d_ws, size_t ws_size,
                              hipStream_t stream) {
    (void)in_sizes; (void)n_in; (void)d_ws; (void)ws_size; (void)out_size;
    const float* x = (const float*)d_in[0];
    float* out = (float*)d_out;
    yin_kernel<<<dim3(8 * BPB), dim3(192), 0, stream>>>(x, out);
}